// Round 3
// baseline (141.654 us; speedup 1.0000x reference)
//
#include <hip/hip_runtime.h>

#define NV 4
#define NB 2048
#define ND 512
#define NN 8192
// sim = cos/TEMP, TEMP=0.5 -> scale 2.0

typedef __bf16 bf16x8 __attribute__((ext_vector_type(8)));
typedef float floatx4 __attribute__((ext_vector_type(4)));

// ---------------- normalize: x[N,D] f32 -> xn[N,D] bf16 (unit rows) --------
// Also zeros sumexp (4 floats per block) and out (block 0) so kernel_launch
// needs no hipMemsetAsync dispatches.
__global__ __launch_bounds__(256) void normalize_k(const float* __restrict__ x,
                                                   __bf16* __restrict__ xn,
                                                   float* __restrict__ sumexp,
                                                   float* __restrict__ out) {
  if (threadIdx.x < 4) sumexp[blockIdx.x * 4 + threadIdx.x] = 0.0f;
  if (blockIdx.x == 0 && threadIdx.x == 0) out[0] = 0.0f;

  const int row = blockIdx.x * 4 + (threadIdx.x >> 6);  // one wave per row
  const int l = threadIdx.x & 63;                        // lane: cols [8l, 8l+8)
  const float4* xr = (const float4*)(x + (size_t)row * ND);
  float4 v0 = xr[l * 2 + 0];
  float4 v1 = xr[l * 2 + 1];
  float ss = v0.x * v0.x + v0.y * v0.y + v0.z * v0.z + v0.w * v0.w +
             v1.x * v1.x + v1.y * v1.y + v1.z * v1.z + v1.w * v1.w;
#pragma unroll
  for (int off = 32; off > 0; off >>= 1) ss += __shfl_xor(ss, off, 64);
  const float inv = 1.0f / fmaxf(sqrtf(ss), 1e-8f);
  bf16x8 o;
  o[0] = (__bf16)(v0.x * inv); o[1] = (__bf16)(v0.y * inv);
  o[2] = (__bf16)(v0.z * inv); o[3] = (__bf16)(v0.w * inv);
  o[4] = (__bf16)(v1.x * inv); o[5] = (__bf16)(v1.y * inv);
  o[6] = (__bf16)(v1.z * inv); o[7] = (__bf16)(v1.w * inv);
  *(bf16x8*)(xn + (size_t)row * ND + l * 8) = o;
}

// ---------------- async global->LDS, 16B per lane --------------------------
__device__ __forceinline__ void gl_lds16(const void* g, void* l) {
  __builtin_amdgcn_global_load_lds(
      (const __attribute__((address_space(1))) void*)g,
      (__attribute__((address_space(3))) void*)l, 16, 0, 0);
}

// ---------------- fused sim GEMM + exp/mask epilogue, triangular ------------
// S symmetric: only upper-tri tiles (rt<=ct). Off-diag tiles credit BOTH
// sumexp[rows] and sumexp[cols] and both pos mirrors. 2080 blocks.
//
// LDS layout (conflict-free by construction): within each 16-row panel p the
// data is stored k-chunk-major: slot p*64 + c*16 + rr  <- (row p*16+rr, chunk
// c) where chunk = 16 B of k. global_load_lds writes lane l -> base + l*16,
// so lane l stages global (row p*16 + (l&15), chunk l>>4). The MFMA fragment
// read for panel p is then lane l <- p*1024 + l*16: perfectly linear, zero
// bank conflicts (this was +4 cyc per ds_read_b128 with the row-major layout).
__global__ __launch_bounds__(256, 4) void sim_k(const __bf16* __restrict__ xn,
                                                float* __restrict__ sumexp,
                                                float* __restrict__ pos) {
  __shared__ __bf16 As[128 * 32];  // 8 panels x 1024 B
  __shared__ __bf16 Bs[128 * 32];
  const int tid = threadIdx.x;
  const int w = tid >> 6, l = tid & 63;
  const int m = l & 15, q = l >> 4;
  const int wr = w >> 1, wc = w & 1;

  // triangular decode: bid -> (rt, ct), rt <= ct; start(r) = r*64 - r(r-1)/2
  const int bid = blockIdx.x;
  int rt = (int)((129.0f - sqrtf(16641.0f - 8.0f * (float)bid)) * 0.5f);
  rt = rt < 0 ? 0 : (rt > 63 ? 63 : rt);
  while (rt > 0 && (rt * 64 - rt * (rt - 1) / 2) > bid) --rt;
  while (rt < 63 && ((rt + 1) * 64 - (rt + 1) * rt / 2) <= bid) ++rt;
  const int ct = rt + (bid - (rt * 64 - rt * (rt - 1) / 2));
  const bool diag = (rt == ct);

  floatx4 acc[4][4] = {};

  const char* gA = (const char*)xn + (size_t)rt * 128 * (ND * 2);
  const char* gB = (const char*)xn + (size_t)ct * 128 * (ND * 2);
  char* lA = (char*)As;
  char* lB = (char*)Bs;

  // staging lane mapping (k-chunk-major panels): wave w covers rows
  // [w*16, w*16+16) (and +64 for the second issue); lane l -> row w*16+(l&15),
  // k-byte ((l>>4)&3)*16.
  const int rowS = (tid >> 6) * 16 + (tid & 15);
  const int kbS = ((tid >> 4) & 3) * 16;

  for (int kt = 0; kt < ND / 32; ++kt) {
    const int kbyte0 = kt * 64;  // 32 bf16 per K-step
    {
      const char* ga0 = gA + (size_t)rowS * (ND * 2) + kbyte0 + kbS;
      const char* gb0 = gB + (size_t)rowS * (ND * 2) + kbyte0 + kbS;
      const char* ga1 = gA + (size_t)(rowS + 64) * (ND * 2) + kbyte0 + kbS;
      const char* gb1 = gB + (size_t)(rowS + 64) * (ND * 2) + kbyte0 + kbS;
      gl_lds16(ga0, lA + w * 1024);          // wave-uniform base + lane*16
      gl_lds16(gb0, lB + w * 1024);
      gl_lds16(ga1, lA + 4096 + w * 1024);
      gl_lds16(gb1, lB + 4096 + w * 1024);
    }
    __syncthreads();
    bf16x8 af[4], bfr[4];
#pragma unroll
    for (int mt = 0; mt < 4; ++mt)   // panel (wr*4+mt), lane-linear read
      af[mt] = *(const bf16x8*)(lA + (wr * 4 + mt) * 1024 + l * 16);
#pragma unroll
    for (int nt = 0; nt < 4; ++nt)
      bfr[nt] = *(const bf16x8*)(lB + (wc * 4 + nt) * 1024 + l * 16);
#pragma unroll
    for (int mt = 0; mt < 4; ++mt)
#pragma unroll
      for (int nt = 0; nt < 4; ++nt)
        acc[mt][nt] = __builtin_amdgcn_mfma_f32_16x16x32_bf16(
            af[mt], bfr[nt], acc[mt][nt], 0, 0, 0);
    __syncthreads();  // all waves done reading before next overwrite
  }

  // epilogue: s = 2*acc; masked cols ((c-r)%B==0) store pos, skip sums.
  // Row sums always; col sums + pos mirror only on off-diagonal tiles.
  const int r0 = rt * 128 + wr * 64;
  const int c0 = ct * 128 + wc * 64;
  float cs[4] = {0.f, 0.f, 0.f, 0.f};  // per-nt column partials (this lane's q)
#pragma unroll
  for (int mt = 0; mt < 4; ++mt) {
    float rs[4] = {0.f, 0.f, 0.f, 0.f};
#pragma unroll
    for (int nt = 0; nt < 4; ++nt) {
      const int c = c0 + nt * 16 + m;  // C layout: col = lane&15
#pragma unroll
      for (int reg = 0; reg < 4; ++reg) {
        const int r = r0 + mt * 16 + q * 4 + reg;  // row = quad*4 + reg
        const float s = acc[mt][nt][reg] * 2.0f;
        if (((c - r) & (NB - 1)) == 0) {
          pos[r * NV + (c >> 11)] = s;  // includes j==i (unused later)
          if (!diag) pos[c * NV + (r >> 11)] = s;
        } else {
          const float e = __expf(s);
          rs[reg] += e;
          cs[nt] += e;
        }
      }
    }
    // reduce rows across the 16-lane column dimension (m)
#pragma unroll
    for (int off = 1; off < 16; off <<= 1) {
#pragma unroll
      for (int reg = 0; reg < 4; ++reg) rs[reg] += __shfl_xor(rs[reg], off, 64);
    }
    if (m < 4) atomicAdd(&sumexp[r0 + mt * 16 + q * 4 + m], rs[m]);
  }
  if (!diag) {
    // reduce cols across the 4-quad row dimension (q)
#pragma unroll
    for (int nt = 0; nt < 4; ++nt) {
      cs[nt] += __shfl_xor(cs[nt], 16, 64);
      cs[nt] += __shfl_xor(cs[nt], 32, 64);
    }
    if (q == 0) {
#pragma unroll
      for (int nt = 0; nt < 4; ++nt)
        atomicAdd(&sumexp[c0 + nt * 16 + m], cs[nt]);
    }
  }
}

// ---------------- finalize: scalar loss -------------------------------------
__global__ __launch_bounds__(256) void finalize_k(
    const float* __restrict__ sumexp, const float* __restrict__ pos,
    float* __restrict__ out) {
  const int r = blockIdx.x * 256 + threadIdx.x;
  const float se = sumexp[r];
  const int i = r >> 11;  // view index
  float local = 0.0f;
#pragma unroll
  for (int j = 0; j < NV; ++j) {
    if (j == i) continue;
    const float p = pos[r * NV + j];
    local += logf(__expf(p) + se) - p;  // logaddexp(pos, lse_neg) - pos
  }
  local *= (1.0f / NB);
#pragma unroll
  for (int off = 32; off > 0; off >>= 1) local += __shfl_xor(local, off, 64);
  if ((threadIdx.x & 63) == 0) atomicAdd(out, local);
}

extern "C" void kernel_launch(void* const* d_in, const int* in_sizes, int n_in,
                              void* d_out, int out_size, void* d_ws,
                              size_t ws_size, hipStream_t stream) {
  const float* x = (const float*)d_in[0];
  float* out = (float*)d_out;
  char* ws = (char*)d_ws;
  __bf16* xn = (__bf16*)ws;                                   // 8 MB
  float* sumexp = (float*)(ws + (size_t)NN * ND * 2);         // 32 KB
  float* pos = (float*)(ws + (size_t)NN * ND * 2 + NN * 4);   // 128 KB

  normalize_k<<<NN / 4, 256, 0, stream>>>(x, xn, sumexp, out);
  sim_k<<<64 * 65 / 2, 256, 0, stream>>>(xn, sumexp, pos);
  finalize_k<<<NN / 256, 256, 0, stream>>>(sumexp, pos, out);
}

// Round 4
// 120.155 us; speedup vs baseline: 1.1789x; 1.1789x over previous
//
#include <hip/hip_runtime.h>

#define NV 4
#define NB 2048
#define ND 512
#define NN 8192
// sim = cos/TEMP, TEMP=0.5 -> scale 2.0

typedef __bf16 bf16x8 __attribute__((ext_vector_type(8)));
typedef float floatx4 __attribute__((ext_vector_type(4)));

// ---------------- normalize: x[N,D] f32 -> xn[N,D] bf16 (unit rows) --------
// Also zeros sumexp (4 floats per block) and out (block 0) so kernel_launch
// needs no hipMemsetAsync dispatches.
__global__ __launch_bounds__(256) void normalize_k(const float* __restrict__ x,
                                                   __bf16* __restrict__ xn,
                                                   float* __restrict__ sumexp,
                                                   float* __restrict__ out) {
  if (threadIdx.x < 4) sumexp[blockIdx.x * 4 + threadIdx.x] = 0.0f;
  if (blockIdx.x == 0 && threadIdx.x == 0) out[0] = 0.0f;

  const int row = blockIdx.x * 4 + (threadIdx.x >> 6);  // one wave per row
  const int l = threadIdx.x & 63;                        // lane: cols [8l, 8l+8)
  const float4* xr = (const float4*)(x + (size_t)row * ND);
  float4 v0 = xr[l * 2 + 0];
  float4 v1 = xr[l * 2 + 1];
  float ss = v0.x * v0.x + v0.y * v0.y + v0.z * v0.z + v0.w * v0.w +
             v1.x * v1.x + v1.y * v1.y + v1.z * v1.z + v1.w * v1.w;
#pragma unroll
  for (int off = 32; off > 0; off >>= 1) ss += __shfl_xor(ss, off, 64);
  const float inv = 1.0f / fmaxf(sqrtf(ss), 1e-8f);
  bf16x8 o;
  o[0] = (__bf16)(v0.x * inv); o[1] = (__bf16)(v0.y * inv);
  o[2] = (__bf16)(v0.z * inv); o[3] = (__bf16)(v0.w * inv);
  o[4] = (__bf16)(v1.x * inv); o[5] = (__bf16)(v1.y * inv);
  o[6] = (__bf16)(v1.z * inv); o[7] = (__bf16)(v1.w * inv);
  *(bf16x8*)(xn + (size_t)row * ND + l * 8) = o;
}

// ---------------- async global->LDS, 16B per lane --------------------------
__device__ __forceinline__ void gl_lds16(const void* g, void* l) {
  __builtin_amdgcn_global_load_lds(
      (const __attribute__((address_space(1))) void*)g,
      (__attribute__((address_space(3))) void*)l, 16, 0, 0);
}

// ---------------- fused sim GEMM + exp/mask epilogue, triangular ------------
// S symmetric: only upper-tri tiles (rt<=ct). Off-diag tiles credit BOTH
// sumexp[rows] and sumexp[cols] and both pos mirrors. 2080 blocks.
//
// LDS layout: row-major [row][k], 64 B/row (no padding — global_load_lds
// writes to wave-uniform base + lane*16). Staging lanes 4k..4k+3 fetch one
// contiguous 64 B row chunk (TA-coalesced; the R3 conflict-free permutation
// scattered lanes 1024 B apart and regressed 34% — DMA slot mapping makes
// "coalesced global" + "conflict-free LDS read" incompatible here, and the
// +4 cyc/b128 read conflict is the cheaper evil).
__global__ __launch_bounds__(256, 4) void sim_k(const __bf16* __restrict__ xn,
                                                float* __restrict__ sumexp,
                                                float* __restrict__ pos) {
  __shared__ __bf16 As[128 * 32];
  __shared__ __bf16 Bs[128 * 32];
  const int tid = threadIdx.x;
  const int w = tid >> 6, l = tid & 63;
  const int m = l & 15, q = l >> 4;
  const int wr = w >> 1, wc = w & 1;

  // triangular decode: bid -> (rt, ct), rt <= ct; start(r) = r*64 - r(r-1)/2
  const int bid = blockIdx.x;
  int rt = (int)((129.0f - sqrtf(16641.0f - 8.0f * (float)bid)) * 0.5f);
  rt = rt < 0 ? 0 : (rt > 63 ? 63 : rt);
  while (rt > 0 && (rt * 64 - rt * (rt - 1) / 2) > bid) --rt;
  while (rt < 63 && ((rt + 1) * 64 - (rt + 1) * rt / 2) <= bid) ++rt;
  const int ct = rt + (bid - (rt * 64 - rt * (rt - 1) / 2));
  const bool diag = (rt == ct);

  floatx4 acc[4][4] = {};

  const char* gA = (const char*)xn + (size_t)rt * 128 * (ND * 2);
  const char* gB = (const char*)xn + (size_t)ct * 128 * (ND * 2);
  char* lA = (char*)As;
  char* lB = (char*)Bs;

  // staging: chunk ch (16B) -> LDS offset ch*16; row = ch>>2, kbyte = (ch&3)*16
  const int row0 = tid >> 2;
  const int kb = (tid & 3) * 16;

  for (int kt = 0; kt < ND / 32; ++kt) {
    const int kbyte0 = kt * 64;  // 32 bf16 per K-step
    {
      const char* ga0 = gA + (size_t)row0 * (ND * 2) + kbyte0 + kb;
      const char* gb0 = gB + (size_t)row0 * (ND * 2) + kbyte0 + kb;
      const char* ga1 = gA + (size_t)(row0 + 64) * (ND * 2) + kbyte0 + kb;
      const char* gb1 = gB + (size_t)(row0 + 64) * (ND * 2) + kbyte0 + kb;
      gl_lds16(ga0, lA + w * 1024);          // wave-uniform base + lane*16
      gl_lds16(gb0, lB + w * 1024);
      gl_lds16(ga1, lA + 4096 + w * 1024);
      gl_lds16(gb1, lB + 4096 + w * 1024);
    }
    __syncthreads();  // compiler emits vmcnt(0) drain before s_barrier
    bf16x8 af[4], bfr[4];
#pragma unroll
    for (int mt = 0; mt < 4; ++mt)
      af[mt] = *(const bf16x8*)(lA + (wr * 64 + mt * 16 + m) * 64 + q * 16);
#pragma unroll
    for (int nt = 0; nt < 4; ++nt)
      bfr[nt] = *(const bf16x8*)(lB + (wc * 64 + nt * 16 + m) * 64 + q * 16);
#pragma unroll
    for (int mt = 0; mt < 4; ++mt)
#pragma unroll
      for (int nt = 0; nt < 4; ++nt)
        acc[mt][nt] = __builtin_amdgcn_mfma_f32_16x16x32_bf16(
            af[mt], bfr[nt], acc[mt][nt], 0, 0, 0);
    __syncthreads();  // all waves done reading before next overwrite
  }

  // epilogue: s = 2*acc; masked cols ((c-r)%B==0) store pos, skip sums.
  // Row sums always; col sums + pos mirror only on off-diagonal tiles.
  const int r0 = rt * 128 + wr * 64;
  const int c0 = ct * 128 + wc * 64;
  float cs[4] = {0.f, 0.f, 0.f, 0.f};  // per-nt column partials (this lane's q)
#pragma unroll
  for (int mt = 0; mt < 4; ++mt) {
    float rs[4] = {0.f, 0.f, 0.f, 0.f};
#pragma unroll
    for (int nt = 0; nt < 4; ++nt) {
      const int c = c0 + nt * 16 + m;  // C layout: col = lane&15
#pragma unroll
      for (int reg = 0; reg < 4; ++reg) {
        const int r = r0 + mt * 16 + q * 4 + reg;  // row = quad*4 + reg
        const float s = acc[mt][nt][reg] * 2.0f;
        if (((c - r) & (NB - 1)) == 0) {
          pos[r * NV + (c >> 11)] = s;  // includes j==i (unused later)
          if (!diag) pos[c * NV + (r >> 11)] = s;
        } else {
          const float e = __expf(s);
          rs[reg] += e;
          cs[nt] += e;
        }
      }
    }
    // reduce rows across the 16-lane column dimension (m)
#pragma unroll
    for (int off = 1; off < 16; off <<= 1) {
#pragma unroll
      for (int reg = 0; reg < 4; ++reg) rs[reg] += __shfl_xor(rs[reg], off, 64);
    }
    if (m < 4) atomicAdd(&sumexp[r0 + mt * 16 + q * 4 + m], rs[m]);
  }
  if (!diag) {
    // reduce cols across the 4-quad row dimension (q)
#pragma unroll
    for (int nt = 0; nt < 4; ++nt) {
      cs[nt] += __shfl_xor(cs[nt], 16, 64);
      cs[nt] += __shfl_xor(cs[nt], 32, 64);
    }
    if (q == 0) {
#pragma unroll
      for (int nt = 0; nt < 4; ++nt)
        atomicAdd(&sumexp[c0 + nt * 16 + m], cs[nt]);
    }
  }
}

// ---------------- finalize: scalar loss -------------------------------------
__global__ __launch_bounds__(256) void finalize_k(
    const float* __restrict__ sumexp, const float* __restrict__ pos,
    float* __restrict__ out) {
  const int r = blockIdx.x * 256 + threadIdx.x;
  const float se = sumexp[r];
  const int i = r >> 11;  // view index
  float local = 0.0f;
#pragma unroll
  for (int j = 0; j < NV; ++j) {
    if (j == i) continue;
    const float p = pos[r * NV + j];
    local += logf(__expf(p) + se) - p;  // logaddexp(pos, lse_neg) - pos
  }
  local *= (1.0f / NB);
#pragma unroll
  for (int off = 32; off > 0; off >>= 1) local += __shfl_xor(local, off, 64);
  if ((threadIdx.x & 63) == 0) atomicAdd(out, local);
}

extern "C" void kernel_launch(void* const* d_in, const int* in_sizes, int n_in,
                              void* d_out, int out_size, void* d_ws,
                              size_t ws_size, hipStream_t stream) {
  const float* x = (const float*)d_in[0];
  float* out = (float*)d_out;
  char* ws = (char*)d_ws;
  __bf16* xn = (__bf16*)ws;                                   // 8 MB
  float* sumexp = (float*)(ws + (size_t)NN * ND * 2);         // 32 KB
  float* pos = (float*)(ws + (size_t)NN * ND * 2 + NN * 4);   // 128 KB

  normalize_k<<<NN / 4, 256, 0, stream>>>(x, xn, sumexp, out);
  sim_k<<<64 * 65 / 2, 256, 0, stream>>>(xn, sumexp, pos);
  finalize_k<<<NN / 256, 256, 0, stream>>>(sumexp, pos, out);
}